// Round 2
// baseline (12943.161 us; speedup 1.0000x reference)
//
#include <hip/hip_runtime.h>
#include <math.h>

#define B_TOT 512
#define T_FR  18
#define NSTEP 16

typedef __attribute__((ext_vector_type(8))) short bf16x8;
typedef __attribute__((ext_vector_type(4))) float f32x4;

__device__ __forceinline__ float gelu_f(float x) {
    return 0.5f * x * (1.0f + erff(x * 0.70710678118654752f));
}
__device__ __forceinline__ float sigmoid_f(float x) {
    return 1.0f / (1.0f + expf(-x));
}
// fp32 -> bf16 RNE, returned as raw short
__device__ __forceinline__ short f2bf(float x) {
    unsigned int u = __float_as_uint(x);
    return (short)((u + 0x7FFFu + ((u >> 16) & 1u)) >> 16);
}

// ---------------------------------------------------------------- init ----
// slots0 = broadcast(slot_mu); rmask = mean over the 128 "c" copies of mask_w;
// w2bf = bf16 copy of enc2 weights (flat layout [co][ci*16+ky*4+kx] == A matrix)
__global__ void init_kernel(const float* __restrict__ slot_mu,
                            const float* __restrict__ mask_w,
                            const float* __restrict__ mask_b,
                            const float* __restrict__ e2w,
                            float* __restrict__ slots_g,
                            float* __restrict__ rmw, float* __restrict__ rmb,
                            short* __restrict__ w2bf) {
    int idx = blockIdx.x * blockDim.x + threadIdx.x;
    const int total = B_TOT * 8 * 128;
    for (int i = idx; i < total; i += gridDim.x * blockDim.x)
        slots_g[i] = slot_mu[i & 1023];
    for (int i = idx; i < 128 * 2048; i += gridDim.x * blockDim.x)
        w2bf[i] = f2bf(e2w[i]);
    if (blockIdx.x == 0) {
        for (int i = threadIdx.x; i < 2048; i += blockDim.x) {
            int j = i >> 7, d = i & 127;
            float s = 0.f;
            for (int c = 0; c < 128; ++c) s += mask_w[(c * 16 + j) * 128 + d];
            rmw[i] = s * (1.0f / 128.0f);
        }
        for (int i = threadIdx.x; i < 16; i += blockDim.x) {
            float s = 0.f;
            for (int c = 0; c < 128; ++c) s += mask_b[c * 16 + i];
            rmb[i] = s * (1.0f / 128.0f);
        }
    }
}

// ------------------------------------------------------------- encoder ----
// per-b block: pair -> gelu(conv3x3) [fp32] -> bf16 MFMA conv4x4/s4 -> fs,kk,vv [fp32]
__global__ __launch_bounds__(256) void encoder_kernel(
    const float* __restrict__ frames,
    const float* __restrict__ e1w, const float* __restrict__ e1b,
    const short* __restrict__ w2bf, const float* __restrict__ e2b,
    const float* __restrict__ tsw, const float* __restrict__ tsb,
    const float* __restrict__ kw,  const float* __restrict__ vw,
    float* __restrict__ kk_g, float* __restrict__ vv_g, int step)
{
    const int b = blockIdx.x;
    const int tid = threadIdx.x;
    const int lane = tid & 63, wv = tid >> 6;
    const int g = lane >> 4, cn = lane & 15;

    __shared__ __align__(16) float s_pair[2 * 256];
    __shared__ __align__(16) float s_e1w[128 * 18];
    __shared__ float s_e1b[128];
    // union region: f1L as bf16 [32 ci][16 rows][20 stride] (10240 shorts = 5120 f32)
    // later: f2T [16][132] f32 (2112) + s_fs [16][132] f32 (2112)
    __shared__ __align__(16) float s_U[5120];
    short* f1s  = (short*)s_U;
    float* f2T  = s_U;
    float* s_fs = s_U + 2112;

    const float* f0  = frames + ((size_t)b * T_FR + step + 1) * 256;
    const float* f1p = frames + ((size_t)b * T_FR + step) * 256;
    s_pair[tid]       = f0[tid];
    s_pair[256 + tid] = f1p[tid];
    for (int i = tid; i < 128 * 18; i += 256) s_e1w[i] = e1w[i];
    if (tid < 128) s_e1b[tid] = e1b[tid];
    __syncthreads();

    // conv1 neighborhood (position = tid), shared across all 128 channels
    const int y = tid >> 4, x = tid & 15;
    float nb0[9], nb1[9];
#pragma unroll
    for (int ky = 0; ky < 3; ++ky)
#pragma unroll
    for (int kx = 0; kx < 3; ++kx) {
        int yy = y + ky - 1, xx = x + kx - 1;
        bool ok = (yy >= 0 && yy < 16 && xx >= 0 && xx < 16);
        nb0[ky * 3 + kx] = ok ? s_pair[yy * 16 + xx] : 0.f;
        nb1[ky * 3 + kx] = ok ? s_pair[256 + yy * 16 + xx] : 0.f;
    }

    // MFMA accumulators: this wave owns output-channel rows [2*wv*16, 2*wv*16+32)
    f32x4 acc0 = {0.f, 0.f, 0.f, 0.f};
    f32x4 acc1 = {0.f, 0.f, 0.f, 0.f};
    const int arow = (2 * wv) * 16 + cn;   // A row for m-tile 0 (m-tile 1 = +16)
    // B-frag base into f1L: lane reads f1[ci_l][4*(n>>2)+qy][4*(n&3)+0..3]
    const int bcol = (4 * (cn >> 2) + (g & 1) * 2) * 20 + 4 * (cn & 3);

    for (int ch = 0; ch < 4; ++ch) {
        const int ci0 = ch * 32;
        // feat1 chunk: 32 channels at this thread's position -> bf16 LDS
#pragma unroll 4
        for (int j = 0; j < 32; ++j) {
            const float* w = &s_e1w[(ci0 + j) * 18];
            float a = s_e1b[ci0 + j];
#pragma unroll
            for (int q = 0; q < 9; ++q) a += nb0[q] * w[q] + nb1[q] * w[q + 9];
            f1s[j * 320 + y * 20 + x] = f2bf(gelu_f(a));
        }
        __syncthreads();
        // MFMA over 16 K-tiles (each = 2 ci)
        int rb = (g >> 1) * 320 + bcol;
        int k0 = (ch * 16) * 32 + g * 8;
        for (int kt = 0; kt < 16; ++kt) {
            const short4 lo = *(const short4*)&f1s[rb];
            const short4 hi = *(const short4*)&f1s[rb + 20];
            bf16x8 bfr;
            bfr[0] = lo.x; bfr[1] = lo.y; bfr[2] = lo.z; bfr[3] = lo.w;
            bfr[4] = hi.x; bfr[5] = hi.y; bfr[6] = hi.z; bfr[7] = hi.w;
            const bf16x8 a0 = *(const bf16x8*)&w2bf[(size_t)arow * 2048 + k0];
            const bf16x8 a1 = *(const bf16x8*)&w2bf[(size_t)(arow + 16) * 2048 + k0];
            acc0 = __builtin_amdgcn_mfma_f32_16x16x32_bf16(a0, bfr, acc0, 0, 0, 0);
            acc1 = __builtin_amdgcn_mfma_f32_16x16x32_bf16(a1, bfr, acc1, 0, 0, 0);
            rb += 640;
            k0 += 32;
        }
        __syncthreads();
    }

    // epilogue: gelu(acc + b) -> f2T[n][co] f32 (D: col=lane&15=n, row=g*4+r+m*16)
    {
        const int cob0 = (2 * wv) * 16 + g * 4;
#pragma unroll
        for (int r = 0; r < 4; ++r)
            f2T[cn * 132 + cob0 + r] = gelu_f(acc0[r] + e2b[cob0 + r]);
        const int cob1 = cob0 + 16;
#pragma unroll
        for (int r = 0; r < 4; ++r)
            f2T[cn * 132 + cob1 + r] = gelu_f(acc1[r] + e2b[cob1 + r]);
    }
    __syncthreads();

    // fs[n][d] = sum_c f2T[n][c]*tsw[d][c] + tsb[d]   (fp32)
    {
        const int d = tid & 127, ng = tid >> 7;
        float a2[8];
#pragma unroll
        for (int i = 0; i < 8; ++i) a2[i] = 0.f;
        for (int c = 0; c < 128; c += 4) {
            const float4 w4 = *reinterpret_cast<const float4*>(&tsw[d * 128 + c]);
#pragma unroll
            for (int i = 0; i < 8; ++i) {
                const float4 f4 = *reinterpret_cast<const float4*>(
                    &f2T[(ng * 8 + i) * 132 + c]);
                a2[i] += w4.x * f4.x + w4.y * f4.y + w4.z * f4.z + w4.w * f4.w;
            }
        }
        const float tb = tsb[d];
#pragma unroll
        for (int i = 0; i < 8; ++i) s_fs[(ng * 8 + i) * 132 + d] = a2[i] + tb;
    }
    __syncthreads();

    // kk[n][j], vv[n][j]  (fp32)
    {
        const int j = tid & 127, ng = tid >> 7;
        float ak[8], av[8];
#pragma unroll
        for (int i = 0; i < 8; ++i) { ak[i] = 0.f; av[i] = 0.f; }
        for (int d = 0; d < 128; d += 4) {
            const float4 wk = *reinterpret_cast<const float4*>(&kw[j * 128 + d]);
            const float4 wvv = *reinterpret_cast<const float4*>(&vw[j * 128 + d]);
#pragma unroll
            for (int i = 0; i < 8; ++i) {
                const float4 f4 = *reinterpret_cast<const float4*>(
                    &s_fs[(ng * 8 + i) * 132 + d]);
                ak[i] += wk.x * f4.x + wk.y * f4.y + wk.z * f4.z + wk.w * f4.w;
                av[i] += wvv.x * f4.x + wvv.y * f4.y + wvv.z * f4.z + wvv.w * f4.w;
            }
        }
#pragma unroll
        for (int i = 0; i < 8; ++i) {
            const int n = ng * 8 + i;
            kk_g[((size_t)b * 16 + n) * 128 + j] = ak[i];
            vv_g[((size_t)b * 16 + n) * 128 + j] = av[i];
        }
    }
}

// ---------------------------------------------------- slot update + decode ----
__global__ __launch_bounds__(256) void slot_update_kernel(
    const float* __restrict__ frames,
    const float* __restrict__ qw,
    const float* __restrict__ wih, const float* __restrict__ whh,
    const float* __restrict__ bih, const float* __restrict__ bhh,
    const float* __restrict__ m1w, const float* __restrict__ m1b,
    const float* __restrict__ m2w, const float* __restrict__ m2b,
    const float* __restrict__ upw, const float* __restrict__ upb,
    const float* __restrict__ r1w, const float* __restrict__ r1b,
    const float* __restrict__ r2w, const float* __restrict__ r2b,
    const float* __restrict__ rmw, const float* __restrict__ rmb,
    float* __restrict__ slots_g,
    const float* __restrict__ kk_g, const float* __restrict__ vv_g,
    float* __restrict__ out, int step)
{
    const int b = blockIdx.x, tid = threadIdx.x;
    __shared__ __align__(16) float s_slots[1024];
    __shared__ __align__(16) float s_kk[16 * 132];   // padded stride: no 16-way conflict
    __shared__ __align__(16) float s_vv[16 * 132];
    __shared__ __align__(16) float s_qq[1024];       // qq, then upd (GRU x-input)
    __shared__ float s_attn[128];
    __shared__ __align__(16) float s_img[256];
    __shared__ __align__(16) float s_warp[256];
    __shared__ float s_m1[256];
    __shared__ float s_mot[16];
    __shared__ float s_ml[128];
    __shared__ __align__(16) float s_masks[2048];
    __shared__ __align__(16) float s_r1[2048];

#pragma unroll
    for (int i = 0; i < 4; ++i)
        s_slots[tid + 256 * i] = slots_g[(size_t)b * 1024 + tid + 256 * i];
#pragma unroll
    for (int i = 0; i < 8; ++i) {
        const int idx = tid + 256 * i;
        const int n = idx >> 7, j = idx & 127;
        s_kk[n * 132 + j] = kk_g[(size_t)b * 2048 + idx];
        s_vv[n * 132 + j] = vv_g[(size_t)b * 2048 + idx];
    }
    s_img[tid] = frames[((size_t)b * T_FR + step + 1) * 256 + tid];
    __syncthreads();

    const float rscale = 0.08838834764831845f;  // 1/sqrt(128)
    const int k8 = tid >> 5, lg = tid & 31;     // slot, lane-in-group

    for (int iter = 0; iter < 3; ++iter) {
        // qq[k][4lg..4lg+3] = slots[k] . qw rows
        {
            float aq[4] = {0.f, 0.f, 0.f, 0.f};
            for (int d = 0; d < 128; d += 4) {
                const float4 s4 = *reinterpret_cast<const float4*>(&s_slots[k8 * 128 + d]);
#pragma unroll
                for (int jj = 0; jj < 4; ++jj) {
                    const float4 w4 = *reinterpret_cast<const float4*>(
                        &qw[(4 * lg + jj) * 128 + d]);
                    aq[jj] += w4.x * s4.x + w4.y * s4.y + w4.z * s4.z + w4.w * s4.w;
                }
            }
            float4 qv; qv.x = aq[0]; qv.y = aq[1]; qv.z = aq[2]; qv.w = aq[3];
            *reinterpret_cast<float4*>(&s_qq[k8 * 128 + 4 * lg]) = qv;
        }
        __syncthreads();
        // logits
        if (tid < 128) {
            const int k = tid >> 4, n = tid & 15;
            float a = 0.f;
            for (int j = 0; j < 128; j += 4) {
                const float4 q4 = *reinterpret_cast<const float4*>(&s_qq[k * 128 + j]);
                const float4 k4 = *reinterpret_cast<const float4*>(&s_kk[n * 132 + j]);
                a += q4.x * k4.x + q4.y * k4.y + q4.z * k4.z + q4.w * k4.w;
            }
            s_attn[k * 16 + n] = a * rscale;
        }
        __syncthreads();
        // softmax over slots k, per n
        if (tid < 16) {
            const int n = tid;
            float m = -1e30f;
#pragma unroll
            for (int k = 0; k < 8; ++k) m = fmaxf(m, s_attn[k * 16 + n]);
            float e[8], ssum = 0.f;
#pragma unroll
            for (int k = 0; k < 8; ++k) { e[k] = expf(s_attn[k * 16 + n] - m); ssum += e[k]; }
            const float inv = 1.f / ssum;
#pragma unroll
            for (int k = 0; k < 8; ++k) s_attn[k * 16 + n] = e[k] * inv;
        }
        __syncthreads();
        // upd[k][d] into s_qq (float4 per thread)
        {
            float4 acc; acc.x = 0.f; acc.y = 0.f; acc.z = 0.f; acc.w = 0.f;
#pragma unroll
            for (int n = 0; n < 16; ++n) {
                const float a = s_attn[k8 * 16 + n];
                const float4 v4 = *reinterpret_cast<const float4*>(&s_vv[n * 132 + 4 * lg]);
                acc.x += a * v4.x; acc.y += a * v4.y; acc.z += a * v4.z; acc.w += a * v4.w;
            }
            *reinterpret_cast<float4*>(&s_qq[k8 * 128 + 4 * lg]) = acc;
        }
        __syncthreads();
        // GRU: 3 gate passes (r,z,n); combine fully in registers.
        float rr[4], zz[4], hnew[4];
#pragma unroll
        for (int p = 0; p < 3; ++p) {
            float aI[4] = {0.f, 0.f, 0.f, 0.f};
            float aH[4] = {0.f, 0.f, 0.f, 0.f};
            for (int d = 0; d < 128; d += 4) {
                const float4 u4 = *reinterpret_cast<const float4*>(&s_qq[k8 * 128 + d]);
                const float4 h4 = *reinterpret_cast<const float4*>(&s_slots[k8 * 128 + d]);
#pragma unroll
                for (int m = 0; m < 4; ++m) {
                    const int j = p * 128 + lg + 32 * m;
                    const float4 wi4 = *reinterpret_cast<const float4*>(&wih[j * 128 + d]);
                    const float4 wh4 = *reinterpret_cast<const float4*>(&whh[j * 128 + d]);
                    aI[m] += wi4.x * u4.x + wi4.y * u4.y + wi4.z * u4.z + wi4.w * u4.w;
                    aH[m] += wh4.x * h4.x + wh4.y * h4.y + wh4.z * h4.z + wh4.w * h4.w;
                }
            }
#pragma unroll
            for (int m = 0; m < 4; ++m) {
                const int j = p * 128 + lg + 32 * m;
                const float gi = aI[m] + bih[j];
                const float gh = aH[m] + bhh[j];
                if (p == 0) rr[m] = sigmoid_f(gi + gh);
                else if (p == 1) zz[m] = sigmoid_f(gi + gh);
                else {
                    const float nn = tanhf(gi + rr[m] * gh);
                    const float hold = s_slots[k8 * 128 + lg + 32 * m];
                    hnew[m] = (1.f - zz[m]) * nn + zz[m] * hold;
                }
            }
        }
        __syncthreads();
#pragma unroll
        for (int m = 0; m < 4; ++m)
            s_slots[k8 * 128 + lg + 32 * m] = hnew[m];
        __syncthreads();
    }

    // persist slots for next step
#pragma unroll
    for (int i = 0; i < 4; ++i)
        slots_g[(size_t)b * 1024 + tid + 256 * i] = s_slots[tid + 256 * i];

    // -------- phase B: motion / ml / masks --------
    {
        const int k = tid >> 5, c = tid & 31;
        float a = m1b[c];
        for (int d = 0; d < 128; d += 4) {
            const float4 w4 = *reinterpret_cast<const float4*>(&m1w[c * 128 + d]);
            const float4 s4 = *reinterpret_cast<const float4*>(&s_slots[k * 128 + d]);
            a += w4.x * s4.x + w4.y * s4.y + w4.z * s4.z + w4.w * s4.w;
        }
        s_m1[k * 32 + c] = gelu_f(a);
    }
    __syncthreads();
    if (tid < 16) {
        const int k = tid >> 1, e = tid & 1;
        float a = m2b[e];
#pragma unroll
        for (int c = 0; c < 32; ++c) a += s_m1[k * 32 + c] * m2w[e * 32 + c];
        s_mot[k * 2 + e] = tanhf(a) * 4.0f;
    }
    if (tid >= 64 && tid < 192) {
        const int q = tid - 64;
        const int k = q >> 4, j = q & 15;
        float a = rmb[j];
        for (int d = 0; d < 128; d += 4) {
            const float4 w4 = *reinterpret_cast<const float4*>(&rmw[j * 128 + d]);
            const float4 s4 = *reinterpret_cast<const float4*>(&s_slots[k * 128 + d]);
            a += w4.x * s4.x + w4.y * s4.y + w4.z * s4.z + w4.w * s4.w;
        }
        s_ml[k * 16 + j] = a;
    }
    __syncthreads();
    // transposed-conv mask logits (non-overlapping stride-4 kernel-4)
#pragma unroll
    for (int i = 0; i < 8; ++i) {
        const int o = tid + 256 * i;
        const int ko = o >> 8, yy = (o >> 4) & 15, xx = o & 15;
        const int jj = (yy >> 2) * 4 + (xx >> 2);
        const int wq = (yy & 3) * 4 + (xx & 3);
        float a = upb[ko];
#pragma unroll
        for (int i8 = 0; i8 < 8; ++i8)
            a += s_ml[i8 * 16 + jj] * upw[(i8 * 8 + ko) * 16 + wq];
        s_masks[ko * 256 + yy * 16 + xx] = a;
    }
    __syncthreads();
    // softmax over the 8 masks per pixel
    {
        float m = -1e30f;
#pragma unroll
        for (int k = 0; k < 8; ++k) m = fmaxf(m, s_masks[k * 256 + tid]);
        float e[8], ssum = 0.f;
#pragma unroll
        for (int k = 0; k < 8; ++k) { e[k] = expf(s_masks[k * 256 + tid] - m); ssum += e[k]; }
        const float inv = 1.f / ssum;
#pragma unroll
        for (int k = 0; k < 8; ++k) s_masks[k * 256 + tid] = e[k] * inv;
    }
    __syncthreads();
    // -------- phase C: warp + residual + out --------
    {
        const int yy = tid >> 4, xx = tid & 15;
        const float gxv = -1.0f + (2.0f / 15.0f) * xx;
        const float gyv = -1.0f + (2.0f / 15.0f) * yy;
        float wsum = 0.f;
#pragma unroll
        for (int k = 0; k < 8; ++k) {
            const float fx = s_mot[k * 2 + 0] * 0.125f;
            const float fy = s_mot[k * 2 + 1] * 0.125f;
            const float sgx = fminf(fmaxf(gxv + fx, -1.f), 1.f);
            const float sgy = fminf(fmaxf(gyv + fy, -1.f), 1.f);
            const float ix = (sgx + 1.f) * 7.5f;
            const float iy = (sgy + 1.f) * 7.5f;
            const float x0f = floorf(ix), y0f = floorf(iy);
            const float wx = ix - x0f, wy = iy - y0f;
            const int x0 = (int)x0f, y0 = (int)y0f;
            const int x1 = min(x0 + 1, 15), y1 = min(y0 + 1, 15);
            const float v00 = s_img[y0 * 16 + x0], v01 = s_img[y0 * 16 + x1];
            const float v10 = s_img[y1 * 16 + x0], v11 = s_img[y1 * 16 + x1];
            const float val = (1.f - wy) * ((1.f - wx) * v00 + wx * v01) +
                              wy * ((1.f - wx) * v10 + wx * v11);
            wsum += s_masks[k * 256 + tid] * val;
        }
        s_warp[tid] = wsum;
    }
    __syncthreads();
    // residual convs, 8-channel chunks
    const int yy = tid >> 4, xx = tid & 15;
    float nbz[9];
#pragma unroll
    for (int ky = 0; ky < 3; ++ky)
#pragma unroll
    for (int kx = 0; kx < 3; ++kx) {
        const int y2 = yy + ky - 1, x2 = xx + kx - 1;
        const bool ok = (y2 >= 0 && y2 < 16 && x2 >= 0 && x2 < 16);
        nbz[ky * 3 + kx] = ok ? (s_warp[y2 * 16 + x2] - s_img[y2 * 16 + x2]) : 0.f;
    }
    float racc = 0.f;
    for (int c0 = 0; c0 < 64; c0 += 8) {
#pragma unroll
        for (int cl = 0; cl < 8; ++cl) {
            const int c = c0 + cl;
            float a = r1b[c];
#pragma unroll
            for (int q = 0; q < 9; ++q) a += nbz[q] * r1w[c * 9 + q];
            s_r1[cl * 256 + tid] = gelu_f(a);
        }
        __syncthreads();
#pragma unroll
        for (int cl = 0; cl < 8; ++cl) {
#pragma unroll
            for (int ky = 0; ky < 3; ++ky)
#pragma unroll
            for (int kx = 0; kx < 3; ++kx) {
                const int y2 = yy + ky - 1, x2 = xx + kx - 1;
                if (y2 >= 0 && y2 < 16 && x2 >= 0 && x2 < 16)
                    racc += s_r1[cl * 256 + y2 * 16 + x2] * r2w[(c0 + cl) * 9 + ky * 3 + kx];
            }
        }
        __syncthreads();
    }
    const float resv = tanhf(racc + r2b[0]) * 0.1f;
    const float pred = fminf(fmaxf(s_warp[tid] + resv, 0.f), 1.f);
    out[((size_t)b * NSTEP + step) * 256 + tid] = pred;
}

// -------------------------------------------------------------- launch ----
extern "C" void kernel_launch(void* const* d_in, const int* in_sizes, int n_in,
                              void* d_out, int out_size, void* d_ws, size_t ws_size,
                              hipStream_t stream)
{
    const float* frames = (const float*)d_in[0];
    const float* e1w = (const float*)d_in[1];
    const float* e1b = (const float*)d_in[2];
    const float* e2w = (const float*)d_in[3];
    const float* e2b = (const float*)d_in[4];
    const float* slot_mu = (const float*)d_in[5];
    const float* tsw = (const float*)d_in[6];
    const float* tsb = (const float*)d_in[7];
    const float* qw = (const float*)d_in[8];
    const float* kw = (const float*)d_in[9];
    const float* vw = (const float*)d_in[10];
    const float* wih = (const float*)d_in[11];
    const float* whh = (const float*)d_in[12];
    const float* bih = (const float*)d_in[13];
    const float* bhh = (const float*)d_in[14];
    const float* m1w = (const float*)d_in[15];
    const float* m1b = (const float*)d_in[16];
    const float* m2w = (const float*)d_in[17];
    const float* m2b = (const float*)d_in[18];
    const float* maskw = (const float*)d_in[19];
    const float* maskb = (const float*)d_in[20];
    const float* upw = (const float*)d_in[21];
    const float* upb = (const float*)d_in[22];
    const float* r1w = (const float*)d_in[23];
    const float* r1b = (const float*)d_in[24];
    const float* r2w = (const float*)d_in[25];
    const float* r2b = (const float*)d_in[26];

    float* ws = (float*)d_ws;
    float* slots_g = ws;                        // 512*1024
    float* kk_g = ws + 524288;                  // 512*2048
    float* vv_g = ws + 1572864;                 // 512*2048
    float* rmw = ws + 2621440;                  // 16*128
    float* rmb = ws + 2623488;                  // 16 (padded to 2623504)
    short* w2bf = (short*)(ws + 2623504);       // 128*2048 bf16

    hipLaunchKernelGGL(init_kernel, dim3(512), dim3(256), 0, stream,
                       slot_mu, maskw, maskb, e2w, slots_g, rmw, rmb, w2bf);
    for (int t = 0; t < NSTEP; ++t) {
        hipLaunchKernelGGL(encoder_kernel, dim3(512), dim3(256), 0, stream,
                           frames, e1w, e1b, w2bf, e2b, tsw, tsb, kw, vw,
                           kk_g, vv_g, t);
        hipLaunchKernelGGL(slot_update_kernel, dim3(512), dim3(256), 0, stream,
                           frames, qw, wih, whh, bih, bhh, m1w, m1b, m2w, m2b,
                           upw, upb, r1w, r1b, r2w, r2b, rmw, rmb,
                           slots_g, kk_g, vv_g, (float*)d_out, t);
    }
}

// Round 3
// 4123.093 us; speedup vs baseline: 3.1392x; 3.1392x over previous
//
#include <hip/hip_runtime.h>
#include <math.h>

#define B_TOT 512
#define T_FR  18
#define NSTEP 16

typedef __attribute__((ext_vector_type(8))) short bf16x8;
typedef __attribute__((ext_vector_type(4))) float f32x4;

__device__ __forceinline__ float gelu_f(float x) {
    return 0.5f * x * (1.0f + erff(x * 0.70710678118654752f));
}
__device__ __forceinline__ float sigmoid_f(float x) {
    return 1.0f / (1.0f + expf(-x));
}
// fp32 -> bf16 RNE, returned as raw short
__device__ __forceinline__ short f2bf(float x) {
    unsigned int u = __float_as_uint(x);
    return (short)((u + 0x7FFFu + ((u >> 16) & 1u)) >> 16);
}

// ---------------------------------------------------------------- init ----
__global__ void init_kernel(const float* __restrict__ slot_mu,
                            const float* __restrict__ mask_w,
                            const float* __restrict__ mask_b,
                            const float* __restrict__ e2w,
                            const float* __restrict__ wih,
                            const float* __restrict__ whh,
                            float* __restrict__ slots_g,
                            float* __restrict__ rmw, float* __restrict__ rmb,
                            short* __restrict__ w2bf,
                            short* __restrict__ wihbf,
                            short* __restrict__ whhbf) {
    int idx = blockIdx.x * blockDim.x + threadIdx.x;
    const int total = B_TOT * 8 * 128;
    for (int i = idx; i < total; i += gridDim.x * blockDim.x)
        slots_g[i] = slot_mu[i & 1023];
    for (int i = idx; i < 128 * 2048; i += gridDim.x * blockDim.x)
        w2bf[i] = f2bf(e2w[i]);
    for (int i = idx; i < 384 * 128; i += gridDim.x * blockDim.x) {
        wihbf[i] = f2bf(wih[i]);
        whhbf[i] = f2bf(whh[i]);
    }
    if (blockIdx.x == 0) {
        for (int i = threadIdx.x; i < 2048; i += blockDim.x) {
            int j = i >> 7, d = i & 127;
            float s = 0.f;
            for (int c = 0; c < 128; ++c) s += mask_w[(c * 16 + j) * 128 + d];
            rmw[i] = s * (1.0f / 128.0f);
        }
        for (int i = threadIdx.x; i < 16; i += blockDim.x) {
            float s = 0.f;
            for (int c = 0; c < 128; ++c) s += mask_b[c * 16 + i];
            rmb[i] = s * (1.0f / 128.0f);
        }
    }
}

// ------------------------------------------------------------- encoder ----
// per-b block: pair -> gelu(conv3x3) [fp32] -> bf16 MFMA conv4x4/s4 -> fs,kk,vv [fp32]
__global__ __launch_bounds__(256) void encoder_kernel(
    const float* __restrict__ frames,
    const float* __restrict__ e1w, const float* __restrict__ e1b,
    const short* __restrict__ w2bf, const float* __restrict__ e2b,
    const float* __restrict__ tsw, const float* __restrict__ tsb,
    const float* __restrict__ kw,  const float* __restrict__ vw,
    float* __restrict__ kk_g, float* __restrict__ vv_g, int step)
{
    const int b = blockIdx.x;
    const int tid = threadIdx.x;
    const int lane = tid & 63, wv = tid >> 6;
    const int g = lane >> 4, cn = lane & 15;

    __shared__ __align__(16) float s_pair[2 * 256];
    __shared__ __align__(16) float s_e1w[128 * 18];
    __shared__ float s_e1b[128];
    __shared__ __align__(16) float s_U[5120];
    short* f1s  = (short*)s_U;
    float* f2T  = s_U;
    float* s_fs = s_U + 2112;

    const float* f0  = frames + ((size_t)b * T_FR + step + 1) * 256;
    const float* f1p = frames + ((size_t)b * T_FR + step) * 256;
    s_pair[tid]       = f0[tid];
    s_pair[256 + tid] = f1p[tid];
    for (int i = tid; i < 128 * 18; i += 256) s_e1w[i] = e1w[i];
    if (tid < 128) s_e1b[tid] = e1b[tid];
    __syncthreads();

    const int y = tid >> 4, x = tid & 15;
    float nb0[9], nb1[9];
#pragma unroll
    for (int ky = 0; ky < 3; ++ky)
#pragma unroll
    for (int kx = 0; kx < 3; ++kx) {
        int yy = y + ky - 1, xx = x + kx - 1;
        bool ok = (yy >= 0 && yy < 16 && xx >= 0 && xx < 16);
        nb0[ky * 3 + kx] = ok ? s_pair[yy * 16 + xx] : 0.f;
        nb1[ky * 3 + kx] = ok ? s_pair[256 + yy * 16 + xx] : 0.f;
    }

    f32x4 acc0 = {0.f, 0.f, 0.f, 0.f};
    f32x4 acc1 = {0.f, 0.f, 0.f, 0.f};
    const int arow = (2 * wv) * 16 + cn;
    const int bcol = (4 * (cn >> 2) + (g & 1) * 2) * 20 + 4 * (cn & 3);

    for (int ch = 0; ch < 4; ++ch) {
        const int ci0 = ch * 32;
#pragma unroll 4
        for (int j = 0; j < 32; ++j) {
            const float* w = &s_e1w[(ci0 + j) * 18];
            float a = s_e1b[ci0 + j];
#pragma unroll
            for (int q = 0; q < 9; ++q) a += nb0[q] * w[q] + nb1[q] * w[q + 9];
            f1s[j * 320 + y * 20 + x] = f2bf(gelu_f(a));
        }
        __syncthreads();
        int rb = (g >> 1) * 320 + bcol;
        int k0 = (ch * 16) * 32 + g * 8;
        for (int kt = 0; kt < 16; ++kt) {
            const short4 lo = *(const short4*)&f1s[rb];
            const short4 hi = *(const short4*)&f1s[rb + 20];
            bf16x8 bfr;
            bfr[0] = lo.x; bfr[1] = lo.y; bfr[2] = lo.z; bfr[3] = lo.w;
            bfr[4] = hi.x; bfr[5] = hi.y; bfr[6] = hi.z; bfr[7] = hi.w;
            const bf16x8 a0 = *(const bf16x8*)&w2bf[(size_t)arow * 2048 + k0];
            const bf16x8 a1 = *(const bf16x8*)&w2bf[(size_t)(arow + 16) * 2048 + k0];
            acc0 = __builtin_amdgcn_mfma_f32_16x16x32_bf16(a0, bfr, acc0, 0, 0, 0);
            acc1 = __builtin_amdgcn_mfma_f32_16x16x32_bf16(a1, bfr, acc1, 0, 0, 0);
            rb += 640;
            k0 += 32;
        }
        __syncthreads();
    }

    {
        const int cob0 = (2 * wv) * 16 + g * 4;
#pragma unroll
        for (int r = 0; r < 4; ++r)
            f2T[cn * 132 + cob0 + r] = gelu_f(acc0[r] + e2b[cob0 + r]);
        const int cob1 = cob0 + 16;
#pragma unroll
        for (int r = 0; r < 4; ++r)
            f2T[cn * 132 + cob1 + r] = gelu_f(acc1[r] + e2b[cob1 + r]);
    }
    __syncthreads();

    {
        const int d = tid & 127, ng = tid >> 7;
        float a2[8];
#pragma unroll
        for (int i = 0; i < 8; ++i) a2[i] = 0.f;
        for (int c = 0; c < 128; c += 4) {
            const float4 w4 = *reinterpret_cast<const float4*>(&tsw[d * 128 + c]);
#pragma unroll
            for (int i = 0; i < 8; ++i) {
                const float4 f4 = *reinterpret_cast<const float4*>(
                    &f2T[(ng * 8 + i) * 132 + c]);
                a2[i] += w4.x * f4.x + w4.y * f4.y + w4.z * f4.z + w4.w * f4.w;
            }
        }
        const float tb = tsb[d];
#pragma unroll
        for (int i = 0; i < 8; ++i) s_fs[(ng * 8 + i) * 132 + d] = a2[i] + tb;
    }
    __syncthreads();

    {
        const int j = tid & 127, ng = tid >> 7;
        float ak[8], av[8];
#pragma unroll
        for (int i = 0; i < 8; ++i) { ak[i] = 0.f; av[i] = 0.f; }
        for (int d = 0; d < 128; d += 4) {
            const float4 wk = *reinterpret_cast<const float4*>(&kw[j * 128 + d]);
            const float4 wvv = *reinterpret_cast<const float4*>(&vw[j * 128 + d]);
#pragma unroll
            for (int i = 0; i < 8; ++i) {
                const float4 f4 = *reinterpret_cast<const float4*>(
                    &s_fs[(ng * 8 + i) * 132 + d]);
                ak[i] += wk.x * f4.x + wk.y * f4.y + wk.z * f4.z + wk.w * f4.w;
                av[i] += wvv.x * f4.x + wvv.y * f4.y + wvv.z * f4.z + wvv.w * f4.w;
            }
        }
#pragma unroll
        for (int i = 0; i < 8; ++i) {
            const int n = ng * 8 + i;
            kk_g[((size_t)b * 16 + n) * 128 + j] = ak[i];
            vv_g[((size_t)b * 16 + n) * 128 + j] = av[i];
        }
    }
}

// ---------------------------------------------------- slot update + decode ----
__global__ __launch_bounds__(256, 3) void slot_update_kernel(
    const float* __restrict__ frames,
    const float* __restrict__ qw,
    const short* __restrict__ wihbf, const short* __restrict__ whhbf,
    const float* __restrict__ bih, const float* __restrict__ bhh,
    const float* __restrict__ m1w, const float* __restrict__ m1b,
    const float* __restrict__ m2w, const float* __restrict__ m2b,
    const float* __restrict__ upw, const float* __restrict__ upb,
    const float* __restrict__ r1w, const float* __restrict__ r1b,
    const float* __restrict__ r2w, const float* __restrict__ r2b,
    const float* __restrict__ rmw, const float* __restrict__ rmb,
    float* __restrict__ slots_g,
    const float* __restrict__ kk_g, const float* __restrict__ vv_g,
    float* __restrict__ out, int step)
{
    const int b = blockIdx.x, tid = threadIdx.x;
    const int lane = tid & 63, w = tid >> 6;
    const int g = lane >> 4, cn = lane & 15;

    __shared__ __align__(16) float s_slots[1024];
    __shared__ __align__(16) short s_slotsbf[2048];   // [16][128], rows 8..15 zero
    __shared__ __align__(16) short s_updbf[2048];     // [16][128], rows 8..15 zero
    __shared__ __align__(16) float s_kv[4224];        // kk[16*132] + vv[16*132]; pool after
    __shared__ __align__(16) float s_qq[1024];
    __shared__ float s_attn[128];
    __shared__ float s_bih[384];
    __shared__ float s_bhh[384];
    __shared__ __align__(16) float s_img[256];
    __shared__ __align__(16) float s_warp[256];

    float* s_kk = s_kv;
    float* s_vv = s_kv + 2112;

#pragma unroll
    for (int i = 0; i < 4; ++i) {
        const int idx = tid + 256 * i;
        const float v = slots_g[(size_t)b * 1024 + idx];
        s_slots[idx] = v;
        s_slotsbf[idx] = f2bf(v);
        s_slotsbf[1024 + idx] = 0;
        s_updbf[1024 + idx] = 0;
    }
#pragma unroll
    for (int i = 0; i < 8; ++i) {
        const int idx = tid + 256 * i;
        const int n = idx >> 7, j = idx & 127;
        s_kk[n * 132 + j] = kk_g[(size_t)b * 2048 + idx];
        s_vv[n * 132 + j] = vv_g[(size_t)b * 2048 + idx];
    }
    for (int i = tid; i < 384; i += 256) { s_bih[i] = bih[i]; s_bhh[i] = bhh[i]; }
    s_img[tid] = frames[((size_t)b * T_FR + step + 1) * 256 + tid];
    __syncthreads();

    const float rscale = 0.08838834764831845f;  // 1/sqrt(128)
    const int k8 = tid >> 5, lg = tid & 31;

    for (int iter = 0; iter < 3; ++iter) {
        // qq[k][j] = slots[k] . qw[j]  (VALU, each qw row read by 2 threads)
        {
            const int j = tid & 127, kb = tid >> 7;
            float aq[4] = {0.f, 0.f, 0.f, 0.f};
            for (int d = 0; d < 128; d += 4) {
                const float4 w4 = *reinterpret_cast<const float4*>(&qw[j * 128 + d]);
#pragma unroll
                for (int i = 0; i < 4; ++i) {
                    const float4 s4 = *reinterpret_cast<const float4*>(
                        &s_slots[(kb + 2 * i) * 128 + d]);
                    aq[i] += w4.x * s4.x + w4.y * s4.y + w4.z * s4.z + w4.w * s4.w;
                }
            }
#pragma unroll
            for (int i = 0; i < 4; ++i) s_qq[(kb + 2 * i) * 128 + j] = aq[i];
        }
        __syncthreads();
        // logits
        if (tid < 128) {
            const int k = tid >> 4, n = tid & 15;
            float a = 0.f;
            for (int j = 0; j < 128; j += 4) {
                const float4 q4 = *reinterpret_cast<const float4*>(&s_qq[k * 128 + j]);
                const float4 k4 = *reinterpret_cast<const float4*>(&s_kk[n * 132 + j]);
                a += q4.x * k4.x + q4.y * k4.y + q4.z * k4.z + q4.w * k4.w;
            }
            s_attn[k * 16 + n] = a * rscale;
        }
        __syncthreads();
        // softmax over slots k, per n
        if (tid < 16) {
            const int n = tid;
            float m = -1e30f;
#pragma unroll
            for (int k = 0; k < 8; ++k) m = fmaxf(m, s_attn[k * 16 + n]);
            float e[8], ssum = 0.f;
#pragma unroll
            for (int k = 0; k < 8; ++k) { e[k] = expf(s_attn[k * 16 + n] - m); ssum += e[k]; }
            const float inv = 1.f / ssum;
#pragma unroll
            for (int k = 0; k < 8; ++k) s_attn[k * 16 + n] = e[k] * inv;
        }
        __syncthreads();
        // upd[k][d] -> bf16 LDS (A matrix for GRU-I GEMM)
        {
            float4 acc; acc.x = 0.f; acc.y = 0.f; acc.z = 0.f; acc.w = 0.f;
#pragma unroll
            for (int n = 0; n < 16; ++n) {
                const float a = s_attn[k8 * 16 + n];
                const float4 v4 = *reinterpret_cast<const float4*>(&s_vv[n * 132 + 4 * lg]);
                acc.x += a * v4.x; acc.y += a * v4.y; acc.z += a * v4.z; acc.w += a * v4.w;
            }
            short4 sv;
            sv.x = f2bf(acc.x); sv.y = f2bf(acc.y); sv.z = f2bf(acc.z); sv.w = f2bf(acc.w);
            *reinterpret_cast<short4*>(&s_updbf[k8 * 128 + 4 * lg]) = sv;
        }
        __syncthreads();

        // ---- GRU via MFMA: D[slot][j] = A[slot][d] * W^T[d][j] ----
        // wave w owns cols [32w, 32w+32) of each of the 3 gates, both GEMMs.
        bf16x8 aU[4], aS[4];
#pragma unroll
        for (int kt = 0; kt < 4; ++kt) {
            aU[kt] = *(const bf16x8*)&s_updbf[cn * 128 + kt * 32 + g * 8];
            aS[kt] = *(const bf16x8*)&s_slotsbf[cn * 128 + kt * 32 + g * 8];
        }
        f32x4 accI[3][2], accH[3][2];
#pragma unroll
        for (int gate = 0; gate < 3; ++gate)
#pragma unroll
        for (int t = 0; t < 2; ++t) {
            accI[gate][t] = (f32x4){0.f, 0.f, 0.f, 0.f};
            accH[gate][t] = (f32x4){0.f, 0.f, 0.f, 0.f};
        }
#pragma unroll
        for (int gate = 0; gate < 3; ++gate)
#pragma unroll
        for (int t = 0; t < 2; ++t) {
            const int jrow = gate * 128 + (2 * w + t) * 16 + cn;
            const int base = jrow * 128 + g * 8;
#pragma unroll
            for (int kt = 0; kt < 4; ++kt) {
                const bf16x8 bI = *(const bf16x8*)&wihbf[base + kt * 32];
                const bf16x8 bH = *(const bf16x8*)&whhbf[base + kt * 32];
                accI[gate][t] = __builtin_amdgcn_mfma_f32_16x16x32_bf16(
                    aU[kt], bI, accI[gate][t], 0, 0, 0);
                accH[gate][t] = __builtin_amdgcn_mfma_f32_16x16x32_bf16(
                    aS[kt], bH, accH[gate][t], 0, 0, 0);
            }
        }
        __syncthreads();   // all A-frag reads done before combine overwrites LDS
        if (g < 2) {
#pragma unroll
            for (int t = 0; t < 2; ++t) {
                const int j = (2 * w + t) * 16 + cn;
#pragma unroll
                for (int r = 0; r < 4; ++r) {
                    const int k = 4 * g + r;
                    const float rr = sigmoid_f(accI[0][t][r] + s_bih[j] +
                                               accH[0][t][r] + s_bhh[j]);
                    const float zz = sigmoid_f(accI[1][t][r] + s_bih[128 + j] +
                                               accH[1][t][r] + s_bhh[128 + j]);
                    const float nn = tanhf(accI[2][t][r] + s_bih[256 + j] +
                                           rr * (accH[2][t][r] + s_bhh[256 + j]));
                    const float hold = s_slots[k * 128 + j];
                    const float hv = (1.f - zz) * nn + zz * hold;
                    s_slots[k * 128 + j] = hv;
                    s_slotsbf[k * 128 + j] = f2bf(hv);
                }
            }
        }
        __syncthreads();
    }

    // persist slots for next step
#pragma unroll
    for (int i = 0; i < 4; ++i)
        slots_g[(size_t)b * 1024 + tid + 256 * i] = s_slots[tid + 256 * i];

    // -------- phase B: motion / ml / masks (aliased onto dead kk/vv) --------
    float* s_m1 = s_kv;            // 8*32
    float* s_mot = s_kv + 256;     // 8*2
    float* s_ml = s_kv + 272;      // 8*16
    float* s_masks = s_kv + 512;   // 8*256
    float* s_r1 = s_kv + 512;      // 8*256 (reuses masks region after warp)
    {
        const int k = tid >> 5, c = tid & 31;
        float a = m1b[c];
        for (int d = 0; d < 128; d += 4) {
            const float4 w4 = *reinterpret_cast<const float4*>(&m1w[c * 128 + d]);
            const float4 s4 = *reinterpret_cast<const float4*>(&s_slots[k * 128 + d]);
            a += w4.x * s4.x + w4.y * s4.y + w4.z * s4.z + w4.w * s4.w;
        }
        s_m1[k * 32 + c] = gelu_f(a);
    }
    __syncthreads();
    if (tid < 16) {
        const int k = tid >> 1, e = tid & 1;
        float a = m2b[e];
#pragma unroll
        for (int c = 0; c < 32; ++c) a += s_m1[k * 32 + c] * m2w[e * 32 + c];
        s_mot[k * 2 + e] = tanhf(a) * 4.0f;
    }
    if (tid >= 64 && tid < 192) {
        const int q = tid - 64;
        const int k = q >> 4, j = q & 15;
        float a = rmb[j];
        for (int d = 0; d < 128; d += 4) {
            const float4 w4 = *reinterpret_cast<const float4*>(&rmw[j * 128 + d]);
            const float4 s4 = *reinterpret_cast<const float4*>(&s_slots[k * 128 + d]);
            a += w4.x * s4.x + w4.y * s4.y + w4.z * s4.z + w4.w * s4.w;
        }
        s_ml[k * 16 + j] = a;
    }
    __syncthreads();
    // transposed-conv mask logits (non-overlapping stride-4 kernel-4)
#pragma unroll
    for (int i = 0; i < 8; ++i) {
        const int o = tid + 256 * i;
        const int ko = o >> 8, yy = (o >> 4) & 15, xx = o & 15;
        const int jj = (yy >> 2) * 4 + (xx >> 2);
        const int wq = (yy & 3) * 4 + (xx & 3);
        float a = upb[ko];
#pragma unroll
        for (int i8 = 0; i8 < 8; ++i8)
            a += s_ml[i8 * 16 + jj] * upw[(i8 * 8 + ko) * 16 + wq];
        s_masks[ko * 256 + yy * 16 + xx] = a;
    }
    __syncthreads();
    // softmax over the 8 masks per pixel
    {
        float m = -1e30f;
#pragma unroll
        for (int k = 0; k < 8; ++k) m = fmaxf(m, s_masks[k * 256 + tid]);
        float e[8], ssum = 0.f;
#pragma unroll
        for (int k = 0; k < 8; ++k) { e[k] = expf(s_masks[k * 256 + tid] - m); ssum += e[k]; }
        const float inv = 1.f / ssum;
#pragma unroll
        for (int k = 0; k < 8; ++k) s_masks[k * 256 + tid] = e[k] * inv;
    }
    __syncthreads();
    // -------- phase C: warp + residual + out --------
    {
        const int yy = tid >> 4, xx = tid & 15;
        const float gxv = -1.0f + (2.0f / 15.0f) * xx;
        const float gyv = -1.0f + (2.0f / 15.0f) * yy;
        float wsum = 0.f;
#pragma unroll
        for (int k = 0; k < 8; ++k) {
            const float fx = s_mot[k * 2 + 0] * 0.125f;
            const float fy = s_mot[k * 2 + 1] * 0.125f;
            const float sgx = fminf(fmaxf(gxv + fx, -1.f), 1.f);
            const float sgy = fminf(fmaxf(gyv + fy, -1.f), 1.f);
            const float ix = (sgx + 1.f) * 7.5f;
            const float iy = (sgy + 1.f) * 7.5f;
            const float x0f = floorf(ix), y0f = floorf(iy);
            const float wx = ix - x0f, wy = iy - y0f;
            const int x0 = (int)x0f, y0 = (int)y0f;
            const int x1 = min(x0 + 1, 15), y1 = min(y0 + 1, 15);
            const float v00 = s_img[y0 * 16 + x0], v01 = s_img[y0 * 16 + x1];
            const float v10 = s_img[y1 * 16 + x0], v11 = s_img[y1 * 16 + x1];
            const float val = (1.f - wy) * ((1.f - wx) * v00 + wx * v01) +
                              wy * ((1.f - wx) * v10 + wx * v11);
            wsum += s_masks[k * 256 + tid] * val;
        }
        s_warp[tid] = wsum;
    }
    __syncthreads();
    // residual convs, 8-channel chunks
    const int yy = tid >> 4, xx = tid & 15;
    float nbz[9];
#pragma unroll
    for (int ky = 0; ky < 3; ++ky)
#pragma unroll
    for (int kx = 0; kx < 3; ++kx) {
        const int y2 = yy + ky - 1, x2 = xx + kx - 1;
        const bool ok = (y2 >= 0 && y2 < 16 && x2 >= 0 && x2 < 16);
        nbz[ky * 3 + kx] = ok ? (s_warp[y2 * 16 + x2] - s_img[y2 * 16 + x2]) : 0.f;
    }
    float racc = 0.f;
    for (int c0 = 0; c0 < 64; c0 += 8) {
#pragma unroll
        for (int cl = 0; cl < 8; ++cl) {
            const int c = c0 + cl;
            float a = r1b[c];
#pragma unroll
            for (int q = 0; q < 9; ++q) a += nbz[q] * r1w[c * 9 + q];
            s_r1[cl * 256 + tid] = gelu_f(a);
        }
        __syncthreads();
#pragma unroll
        for (int cl = 0; cl < 8; ++cl) {
#pragma unroll
            for (int ky = 0; ky < 3; ++ky)
#pragma unroll
            for (int kx = 0; kx < 3; ++kx) {
                const int y2 = yy + ky - 1, x2 = xx + kx - 1;
                if (y2 >= 0 && y2 < 16 && x2 >= 0 && x2 < 16)
                    racc += s_r1[cl * 256 + y2 * 16 + x2] * r2w[(c0 + cl) * 9 + ky * 3 + kx];
            }
        }
        __syncthreads();
    }
    const float resv = tanhf(racc + r2b[0]) * 0.1f;
    const float pred = fminf(fmaxf(s_warp[tid] + resv, 0.f), 1.f);
    out[((size_t)b * NSTEP + step) * 256 + tid] = pred;
}

// -------------------------------------------------------------- launch ----
extern "C" void kernel_launch(void* const* d_in, const int* in_sizes, int n_in,
                              void* d_out, int out_size, void* d_ws, size_t ws_size,
                              hipStream_t stream)
{
    const float* frames = (const float*)d_in[0];
    const float* e1w = (const float*)d_in[1];
    const float* e1b = (const float*)d_in[2];
    const float* e2w = (const float*)d_in[3];
    const float* e2b = (const float*)d_in[4];
    const float* slot_mu = (const float*)d_in[5];
    const float* tsw = (const float*)d_in[6];
    const float* tsb = (const float*)d_in[7];
    const float* qw = (const float*)d_in[8];
    const float* kw = (const float*)d_in[9];
    const float* vw = (const float*)d_in[10];
    const float* wih = (const float*)d_in[11];
    const float* whh = (const float*)d_in[12];
    const float* bih = (const float*)d_in[13];
    const float* bhh = (const float*)d_in[14];
    const float* m1w = (const float*)d_in[15];
    const float* m1b = (const float*)d_in[16];
    const float* m2w = (const float*)d_in[17];
    const float* m2b = (const float*)d_in[18];
    const float* maskw = (const float*)d_in[19];
    const float* maskb = (const float*)d_in[20];
    const float* upw = (const float*)d_in[21];
    const float* upb = (const float*)d_in[22];
    const float* r1w = (const float*)d_in[23];
    const float* r1b = (const float*)d_in[24];
    const float* r2w = (const float*)d_in[25];
    const float* r2b = (const float*)d_in[26];

    float* ws = (float*)d_ws;
    float* slots_g = ws;                        // 512*1024            = 524288
    float* kk_g = ws + 524288;                  // 512*2048            = 1048576
    float* vv_g = ws + 1572864;                 // 512*2048            = 1048576
    float* rmw = ws + 2621440;                  // 2048
    float* rmb = ws + 2623488;                  // 16
    short* w2bf = (short*)(ws + 2623504);       // 262144 shorts = 131072 floats
    short* wihbf = (short*)(ws + 2754576);      // 49152 shorts = 24576 floats
    short* whhbf = (short*)(ws + 2779152);      // 49152 shorts = 24576 floats

    hipLaunchKernelGGL(init_kernel, dim3(512), dim3(256), 0, stream,
                       slot_mu, maskw, maskb, e2w, wih, whh,
                       slots_g, rmw, rmb, w2bf, wihbf, whhbf);
    for (int t = 0; t < NSTEP; ++t) {
        hipLaunchKernelGGL(encoder_kernel, dim3(512), dim3(256), 0, stream,
                           frames, e1w, e1b, w2bf, e2b, tsw, tsb, kw, vw,
                           kk_g, vv_g, t);
        hipLaunchKernelGGL(slot_update_kernel, dim3(512), dim3(256), 0, stream,
                           frames, qw, wihbf, whhbf, bih, bhh, m1w, m1b, m2w, m2b,
                           upw, upb, r1w, r1b, r2w, r2b, rmw, rmb,
                           slots_g, kk_g, vv_g, (float*)d_out, t);
    }
}